// Round 1
// baseline (5949.762 us; speedup 1.0000x reference)
//
#include <hip/hip_runtime.h>
#include <hip/hip_bf16.h>

#define K_NN 32
#define KTOT 33
#define BN_EPS 1e-5f

// ---------------------------------------------------------------- sq norms
template<int F>
__global__ void sqnorm_kernel(const float* __restrict__ x, float* __restrict__ sq, int total) {
    int i = blockIdx.x * blockDim.x + threadIdx.x;
    if (i >= total) return;
    float s = 0.f;
#pragma unroll
    for (int f = 0; f < F; ++f) { float v = x[(size_t)i * F + f]; s += v * v; }
    sq[i] = s;
}

// ---------------------------------------------------------------- knn scan
// grid = B * (N/256) * CS ; block = 256 ; each thread owns one row and scans
// its column chunk, keeping a sorted top-32 (ascending distance).
template<int F>
__global__ __launch_bounds__(256, 1) void knn_scan_kernel(
        const float* __restrict__ feat, const float* __restrict__ sq,
        float* __restrict__ cand_d, int* __restrict__ cand_i, int N, int CS) {
    constexpr int TJ = 64;
    int bpb  = (N / 256) * CS;
    int b    = blockIdx.x / bpb;
    int rem  = blockIdx.x % bpb;
    int rblk = rem / CS;
    int cs   = rem % CS;
    int row  = rblk * 256 + threadIdx.x;
    int chunk = N / CS;
    int c0    = cs * chunk;

    const float* fb  = feat + (size_t)b * N * F;
    const float* sqb = sq + (size_t)b * N;

    float rowf[F];
#pragma unroll
    for (int f = 0; f < F; ++f) rowf[f] = fb[(size_t)row * F + f];
    float sqi = sqb[row];

    float topd[K_NN];
    int   topi[K_NN];
    for (int t = 0; t < K_NN; ++t) { topd[t] = 1e30f; topi[t] = 0; }

    __shared__ float tile[TJ * F];
    __shared__ float tsq[TJ];

    for (int j0 = c0; j0 < c0 + chunk; j0 += TJ) {
        __syncthreads();
        for (int t = threadIdx.x; t < TJ * F; t += 256) tile[t] = fb[(size_t)j0 * F + t];
        for (int t = threadIdx.x; t < TJ; t += 256) tsq[t] = sqb[j0 + t];
        __syncthreads();
        for (int jj = 0; jj < TJ; ++jj) {
            int j = j0 + jj;
            const float* tp = &tile[jj * F];
            float a0 = 0.f, a1 = 0.f, a2 = 0.f, a3 = 0.f;
#pragma unroll
            for (int f = 0; f + 3 < F; f += 4) {
                a0 += rowf[f]     * tp[f];
                a1 += rowf[f + 1] * tp[f + 1];
                a2 += rowf[f + 2] * tp[f + 2];
                a3 += rowf[f + 3] * tp[f + 3];
            }
#pragma unroll
            for (int f = F & ~3; f < F; ++f) a0 += rowf[f] * tp[f];
            float d = sqi + tsq[jj] - 2.f * ((a0 + a1) + (a2 + a3));
            if (j != row && d < topd[K_NN - 1]) {
                int pos = K_NN - 1;
                while (pos > 0 && topd[pos - 1] > d) {
                    topd[pos] = topd[pos - 1]; topi[pos] = topi[pos - 1]; --pos;
                }
                topd[pos] = d; topi[pos] = j;
            }
        }
    }
    size_t base = ((size_t)(b * N + row) * CS + cs) * K_NN;
    for (int t = 0; t < K_NN; ++t) {
        cand_d[base + t] = topd[t];
        cand_i[base + t] = b * N + topi[t];
    }
}

// ---------------------------------------------------------------- knn merge
__global__ void knn_merge_kernel(const float* __restrict__ cand_d,
                                 const int* __restrict__ cand_i,
                                 int* __restrict__ idx_out, int total, int CS) {
    int r = blockIdx.x * blockDim.x + threadIdx.x;
    if (r >= total) return;
    float topd[K_NN];
    int   topi[K_NN];
    for (int t = 0; t < K_NN; ++t) { topd[t] = 1e30f; topi[t] = 0; }
    size_t base = (size_t)r * CS * K_NN;
    for (int c = 0; c < CS * K_NN; ++c) {
        float d = cand_d[base + c];
        if (d < topd[K_NN - 1]) {
            int j = cand_i[base + c];
            int pos = K_NN - 1;
            while (pos > 0 && topd[pos - 1] > d) {
                topd[pos] = topd[pos - 1]; topi[pos] = topi[pos - 1]; --pos;
            }
            topd[pos] = d; topi[pos] = j;
        }
    }
    int* op = idx_out + (size_t)r * KTOT;
    for (int t = 0; t < K_NN; ++t) op[t] = topi[t];
    op[K_NN] = r;
}

// ---------------------------------------------------------------- linear
template<int IN, int OUT>
__global__ void linear_kernel(const float* __restrict__ x, const float* __restrict__ W,
                              float* __restrict__ y, int total) {
    int t = blockIdx.x * blockDim.x + threadIdx.x;
    if (t >= total * OUT) return;
    int o = t % OUT;
    int i = t / OUT;
    float a0 = 0.f, a1 = 0.f, a2 = 0.f, a3 = 0.f;
#pragma unroll
    for (int f = 0; f + 3 < IN; f += 4) {
        a0 += x[(size_t)i * IN + f]     * W[(f) * OUT + o];
        a1 += x[(size_t)i * IN + f + 1] * W[(f + 1) * OUT + o];
        a2 += x[(size_t)i * IN + f + 2] * W[(f + 2) * OUT + o];
        a3 += x[(size_t)i * IN + f + 3] * W[(f + 3) * OUT + o];
    }
#pragma unroll
    for (int f = IN & ~3; f < IN; ++f) a0 += x[(size_t)i * IN + f] * W[f * OUT + o];
    y[t] = (a0 + a1) + (a2 + a3);
}

// ---------------------------------------------------------------- scores
template<int H, int C>
__global__ void scores_kernel(const float* __restrict__ xw, const float* __restrict__ att,
                              float* __restrict__ sd, float* __restrict__ ss, int total) {
    int t = blockIdx.x * blockDim.x + threadIdx.x;
    if (t >= total * H) return;
    int h = t % H;
    int i = t / H;
    float d = 0.f, s = 0.f;
#pragma unroll
    for (int c = 0; c < C; ++c) {
        float v = xw[(size_t)i * H * C + h * C + c];
        d += v * att[h * 2 * C + c];
        s += v * att[h * 2 * C + C + c];
    }
    sd[t] = d;
    ss[t] = s;
}

// ---------------------------------------------------------------- gat gather (online softmax)
template<int H, int C>
__global__ void gat_kernel(const float* __restrict__ xw, const float* __restrict__ sd,
                           const float* __restrict__ ss, const int* __restrict__ idx,
                           const float* __restrict__ bias, float slope,
                           float* __restrict__ out, int total) {
    int t = blockIdx.x * blockDim.x + threadIdx.x;
    if (t >= total * H * C) return;
    int c = t % C;
    int h = (t / C) % H;
    int i = t / (H * C);
    const int* ip = idx + (size_t)i * KTOT;
    float sdi = sd[(size_t)i * H + h];
    float m = -1e30f, l = 0.f, acc = 0.f;
    for (int k = 0; k < KTOT; ++k) {
        int j = ip[k];
        float e = sdi + ss[(size_t)j * H + h];
        e = (e >= 0.f) ? e : slope * e;
        float mn = fmaxf(m, e);
        float sc = __expf(m - mn);
        float w  = __expf(e - mn);
        l   = l * sc + w;
        acc = acc * sc + w * xw[(size_t)j * H * C + h * C + c];
        m = mn;
    }
    float r = acc / l;
    if (bias) r += bias[h * C + c];
    out[t] = r;
}

// ---------------------------------------------------------------- prelu
__global__ void prelu_kernel(float* __restrict__ h, const float* __restrict__ p, int n) {
    int i = blockIdx.x * blockDim.x + threadIdx.x;
    if (i >= n) return;
    float v = h[i];
    h[i] = (v >= 0.f) ? v : p[0] * v;
}

// ---------------------------------------------------------------- bn stats (one block per channel)
__global__ void bn_stats_kernel(const float* __restrict__ h, float* __restrict__ stats,
                                int rows, int C) {
    int c = blockIdx.x;
    float s = 0.f, s2 = 0.f;
    for (int r = threadIdx.x; r < rows; r += blockDim.x) {
        float v = h[(size_t)r * C + c];
        s  += v;
        s2 += v * v;
    }
#pragma unroll
    for (int off = 32; off > 0; off >>= 1) {
        s  += __shfl_down(s, off);
        s2 += __shfl_down(s2, off);
    }
    __shared__ float red[2][4];
    int wave = threadIdx.x >> 6;
    int lane = threadIdx.x & 63;
    if (lane == 0) { red[0][wave] = s; red[1][wave] = s2; }
    __syncthreads();
    if (threadIdx.x == 0) {
        float S = 0.f, S2 = 0.f;
        int nw = blockDim.x >> 6;
        for (int w = 0; w < nw; ++w) { S += red[0][w]; S2 += red[1][w]; }
        float mean = S / rows;
        float var  = S2 / rows - mean * mean;
        stats[c * 2]     = mean;
        stats[c * 2 + 1] = rsqrtf(var + BN_EPS);
    }
}

// ---------------------------------------------------------------- bn apply
__global__ void bn_apply_kernel(float* __restrict__ h, const float* __restrict__ stats,
                                const float* __restrict__ g, const float* __restrict__ be,
                                int total, int C) {
    int t = blockIdx.x * blockDim.x + threadIdx.x;
    if (t >= total * C) return;
    int c = t % C;
    h[t] = (h[t] - stats[c * 2]) * stats[c * 2 + 1] * g[c] + be[c];
}

// ---------------------------------------------------------------- final: mean heads + b3, @Wc + bc
__global__ void final_kernel(const float* __restrict__ g3, const float* __restrict__ b3,
                             const float* __restrict__ Wc, const float* __restrict__ bc,
                             float* __restrict__ out, int total) {
    int t = blockIdx.x * blockDim.x + threadIdx.x;
    if (t >= total * 16) return;
    int o = t & 15;
    int i = t >> 4;
    float acc = bc[o];
#pragma unroll
    for (int c = 0; c < 6; ++c) {
        float hm = 0.f;
#pragma unroll
        for (int h = 0; h < 8; ++h) hm += g3[(size_t)i * 48 + h * 6 + c];
        hm = hm * 0.125f + b3[c];
        acc += hm * Wc[c * 16 + o];
    }
    out[t] = acc;
}

static inline int cdiv(int a, int b) { return (a + b - 1) / b; }

extern "C" void kernel_launch(void* const* d_in, const int* in_sizes, int n_in,
                              void* d_out, int out_size, void* d_ws, size_t ws_size,
                              hipStream_t stream) {
    const float* x    = (const float*)d_in[0];
    // d_in[1] = target (unused)
    const float* W1   = (const float*)d_in[2];
    const float* att1 = (const float*)d_in[3];
    const float* b1   = (const float*)d_in[4];
    const float* p1   = (const float*)d_in[5];
    const float* g1   = (const float*)d_in[6];
    const float* be1  = (const float*)d_in[7];
    const float* W2   = (const float*)d_in[8];
    const float* att2 = (const float*)d_in[9];
    const float* b2   = (const float*)d_in[10];
    const float* p2   = (const float*)d_in[11];
    const float* g2   = (const float*)d_in[12];
    const float* be2  = (const float*)d_in[13];
    const float* W3   = (const float*)d_in[14];
    const float* att3 = (const float*)d_in[15];
    const float* b3   = (const float*)d_in[16];
    const float* Wc   = (const float*)d_in[17];
    const float* bc   = (const float*)d_in[18];

    const int B = 8, N = 2048, T = B * N;
    const int CS = 4;

    float* ws    = (float*)d_ws;
    float* xw    = ws;                           // T*128
    float* bufA  = xw   + (size_t)T * 128;       // T*64
    float* bufB  = bufA + (size_t)T * 64;        // T*128
    float* bufC  = bufB + (size_t)T * 128;       // T*48
    float* sd    = bufC + (size_t)T * 48;        // T*8
    float* ss    = sd   + (size_t)T * 8;         // T*8
    float* sq    = ss   + (size_t)T * 8;         // T
    float* stats = sq   + T;                     // 256
    float* cand_d = xw;                          // alias: T*CS*32 == T*128
    int*   cand_i = (int*)(stats + 256);         // T*CS*32
    int*   idx    = cand_i + (size_t)T * CS * K_NN; // T*33
    (void)n_in; (void)in_sizes; (void)ws_size; (void)out_size;

    const int BS = 256;
    int knn_grid = B * (N / 256) * CS;

    // ================= Layer 1 (F=3 -> H=4,C=16 -> 64) =================
    sqnorm_kernel<3><<<cdiv(T, BS), BS, 0, stream>>>(x, sq, T);
    knn_scan_kernel<3><<<knn_grid, 256, 0, stream>>>(x, sq, cand_d, cand_i, N, CS);
    knn_merge_kernel<<<cdiv(T, BS), BS, 0, stream>>>(cand_d, cand_i, idx, T, CS);
    linear_kernel<3, 64><<<cdiv(T * 64, BS), BS, 0, stream>>>(x, W1, xw, T);
    scores_kernel<4, 16><<<cdiv(T * 4, BS), BS, 0, stream>>>(xw, att1, sd, ss, T);
    gat_kernel<4, 16><<<cdiv(T * 64, BS), BS, 0, stream>>>(xw, sd, ss, idx, b1, 0.2f, bufA, T);
    prelu_kernel<<<cdiv(T * 64, BS), BS, 0, stream>>>(bufA, p1, T * 64);
    bn_stats_kernel<<<64, 256, 0, stream>>>(bufA, stats, T, 64);
    bn_apply_kernel<<<cdiv(T * 64, BS), BS, 0, stream>>>(bufA, stats, g1, be1, T, 64);

    // ================= Layer 2 (F=64 -> H=2,C=64 -> 128) =================
    sqnorm_kernel<64><<<cdiv(T, BS), BS, 0, stream>>>(bufA, sq, T);
    knn_scan_kernel<64><<<knn_grid, 256, 0, stream>>>(bufA, sq, cand_d, cand_i, N, CS);
    knn_merge_kernel<<<cdiv(T, BS), BS, 0, stream>>>(cand_d, cand_i, idx, T, CS);
    linear_kernel<64, 128><<<cdiv(T * 128, BS), BS, 0, stream>>>(bufA, W2, xw, T);
    scores_kernel<2, 64><<<cdiv(T * 2, BS), BS, 0, stream>>>(xw, att2, sd, ss, T);
    gat_kernel<2, 64><<<cdiv(T * 128, BS), BS, 0, stream>>>(xw, sd, ss, idx, b2, 0.2f, bufB, T);
    prelu_kernel<<<cdiv(T * 128, BS), BS, 0, stream>>>(bufB, p2, T * 128);
    bn_stats_kernel<<<128, 256, 0, stream>>>(bufB, stats, T, 128);
    bn_apply_kernel<<<cdiv(T * 128, BS), BS, 0, stream>>>(bufB, stats, g2, be2, T, 128);

    // ================= Layer 3 (F=128 -> H=8,C=6 -> mean -> 6) =================
    sqnorm_kernel<128><<<cdiv(T, BS), BS, 0, stream>>>(bufB, sq, T);
    knn_scan_kernel<128><<<knn_grid, 256, 0, stream>>>(bufB, sq, cand_d, cand_i, N, CS);
    knn_merge_kernel<<<cdiv(T, BS), BS, 0, stream>>>(cand_d, cand_i, idx, T, CS);
    linear_kernel<128, 48><<<cdiv(T * 48, BS), BS, 0, stream>>>(bufB, W3, xw, T);
    scores_kernel<8, 6><<<cdiv(T * 8, BS), BS, 0, stream>>>(xw, att3, sd, ss, T);
    gat_kernel<8, 6><<<cdiv(T * 48, BS), BS, 0, stream>>>(xw, sd, ss, idx, nullptr, 0.5f, bufC, T);

    // ================= Final =================
    final_kernel<<<cdiv(T * 16, BS), BS, 0, stream>>>(bufC, b3, Wc, bc, (float*)d_out, T);
}

// Round 2
// 1027.955 us; speedup vs baseline: 5.7880x; 5.7880x over previous
//
#include <hip/hip_runtime.h>
#include <hip/hip_bf16.h>

#define K_NN 32
#define KTOT 33
#define BN_EPS 1e-5f

typedef unsigned int uint32;
typedef unsigned long long ulong64;

__device__ __forceinline__ uint32 key_of(float f) {
    uint32 u = __float_as_uint(f);
    return u ^ ((u & 0x80000000u) ? 0xFFFFFFFFu : 0x80000000u);
}

// ---------------------------------------------------------------- sq norms
template<int F>
__global__ void sqnorm_kernel(const float* __restrict__ x, float* __restrict__ sq, int total) {
    int i = blockIdx.x * blockDim.x + threadIdx.x;
    if (i >= total) return;
    float s = 0.f;
#pragma unroll
    for (int f = 0; f < F; ++f) { float v = x[(size_t)i * F + f]; s += v * v; }
    sq[i] = s;
}

// ---------------------------------------------------------------- distance matrix
// grid = (N/64, N/64, PB), block = 256. Thread computes a 4x4 patch of D.
template<int F>
__global__ __launch_bounds__(256) void dist_kernel(
        const float* __restrict__ X, const float* __restrict__ sq,
        float* __restrict__ D, int N) {
    constexpr int KF = (F < 32) ? F : 32;
    __shared__ float As[KF][68];
    __shared__ float Bs[KF][68];
    int bz = blockIdx.z;
    const float* Xb  = X  + (size_t)bz * N * F;
    const float* sqb = sq + (size_t)bz * N;
    float* Db = D + (size_t)bz * N * N;
    int r0 = blockIdx.y * 64, c0 = blockIdx.x * 64;
    int tid = threadIdx.x;
    int tx = tid & 15, ty = tid >> 4;
    float acc[4][4] = {};
    for (int f0 = 0; f0 < F; f0 += KF) {
        __syncthreads();
        for (int e = tid; e < 64 * KF; e += 256) {
            int r = e / KF, k = e - r * KF;
            As[k][r] = Xb[(size_t)(r0 + r) * F + f0 + k];
            Bs[k][r] = Xb[(size_t)(c0 + r) * F + f0 + k];
        }
        __syncthreads();
#pragma unroll
        for (int k = 0; k < KF; ++k) {
            float a0 = As[k][ty * 4], a1 = As[k][ty * 4 + 1],
                  a2 = As[k][ty * 4 + 2], a3 = As[k][ty * 4 + 3];
            float b0 = Bs[k][tx * 4], b1 = Bs[k][tx * 4 + 1],
                  b2 = Bs[k][tx * 4 + 2], b3 = Bs[k][tx * 4 + 3];
            acc[0][0] += a0 * b0; acc[0][1] += a0 * b1; acc[0][2] += a0 * b2; acc[0][3] += a0 * b3;
            acc[1][0] += a1 * b0; acc[1][1] += a1 * b1; acc[1][2] += a1 * b2; acc[1][3] += a1 * b3;
            acc[2][0] += a2 * b0; acc[2][1] += a2 * b1; acc[2][2] += a2 * b2; acc[2][3] += a2 * b3;
            acc[3][0] += a3 * b0; acc[3][1] += a3 * b1; acc[3][2] += a3 * b2; acc[3][3] += a3 * b3;
        }
    }
    float sr[4], sc[4];
#pragma unroll
    for (int i = 0; i < 4; ++i) { sr[i] = sqb[r0 + ty * 4 + i]; sc[i] = sqb[c0 + tx * 4 + i]; }
#pragma unroll
    for (int i = 0; i < 4; ++i) {
        int gr = r0 + ty * 4 + i;
#pragma unroll
        for (int j = 0; j < 4; ++j) {
            int gc = c0 + tx * 4 + j;
            float d = sr[i] + sc[j] - 2.f * acc[i][j];
            if (gr == gc) d = 1e30f;
            Db[(size_t)gr * N + gc] = d;
        }
    }
}

// ---------------------------------------------------------------- radix top-32 per row
// One block (256 threads) per row. 4x 8-bit radix passes on monotone keys,
// then deterministic index-ordered collection (smallest-index tie-break).
__global__ __launch_bounds__(256) void knn_select_kernel(
        const float* __restrict__ D, int* __restrict__ idx_out, int b0, int N) {
    int row = blockIdx.x;
    int b   = b0 + row / N;
    int i   = row - (row / N) * N;
    const float* drow = D + (size_t)row * N;
    int tid = threadIdx.x;
    __shared__ int hist[256], sA[256], sB[256];
    __shared__ int sh_bin, sh_excl;
    __shared__ int wl[4], we[4], run[2];

    uint32 prefix = 0;
    int need = K_NN;
    for (int shift = 24; shift >= 0; shift -= 8) {
        hist[tid] = 0;
        __syncthreads();
        uint32 himask = (uint32)(~((1ull << (shift + 8)) - 1ull));
        for (int j = tid; j < N; j += 256) {
            uint32 k = key_of(drow[j]);
            if (((k ^ prefix) & himask) == 0)
                atomicAdd(&hist[(k >> shift) & 255], 1);
        }
        __syncthreads();
        sA[tid] = hist[tid];
        __syncthreads();
        int* src = sA; int* dst = sB;
        for (int off = 1; off < 256; off <<= 1) {
            int x = src[tid];
            if (tid >= off) x += src[tid - off];
            dst[tid] = x;
            __syncthreads();
            int* t_ = src; src = dst; dst = t_;
        }
        int incl = src[tid];
        int excl = incl - hist[tid];
        if (excl < need && incl >= need) { sh_bin = tid; sh_excl = excl; }
        __syncthreads();
        prefix |= ((uint32)sh_bin) << shift;
        need -= sh_excl;
        __syncthreads();
    }
    // prefix = exact key of the 32nd smallest; need = #slots among equal keys
    int cl = K_NN - need;
    int gbase = b * N;
    int* op = idx_out + (size_t)(gbase + i) * KTOT;
    if (tid == 0) { run[0] = 0; run[1] = 0; }
    __syncthreads();
    int wv = tid >> 6, ln = tid & 63;
    for (int j0 = 0; j0 < N; j0 += 256) {
        int j = j0 + tid;
        uint32 k = key_of(drow[j]);
        bool less = (k < prefix);
        bool eq   = (k == prefix);
        ulong64 bl = __ballot(less);
        ulong64 be = __ballot(eq);
        if (ln == 0) { wl[wv] = __popcll(bl); we[wv] = __popcll(be); }
        __syncthreads();
        int offl = run[0], offe = run[1];
        for (int w = 0; w < wv; ++w) { offl += wl[w]; offe += we[w]; }
        ulong64 lomask = (1ull << ln) - 1ull;
        if (less) op[offl + __popcll(bl & lomask)] = gbase + j;
        if (eq) {
            int slot = cl + offe + __popcll(be & lomask);
            if (slot < K_NN) op[slot] = gbase + j;
        }
        __syncthreads();
        if (tid == 0) {
            int tl = 0, te = 0;
            for (int w = 0; w < 4; ++w) { tl += wl[w]; te += we[w]; }
            run[0] += tl; run[1] += te;
        }
        __syncthreads();
    }
    if (tid == 0) op[K_NN] = gbase + i;
}

// ---------------------------------------------------------------- linear
template<int IN, int OUT>
__global__ void linear_kernel(const float* __restrict__ x, const float* __restrict__ W,
                              float* __restrict__ y, int total) {
    int t = blockIdx.x * blockDim.x + threadIdx.x;
    if (t >= total * OUT) return;
    int o = t % OUT;
    int i = t / OUT;
    float a0 = 0.f, a1 = 0.f, a2 = 0.f, a3 = 0.f;
#pragma unroll
    for (int f = 0; f + 3 < IN; f += 4) {
        a0 += x[(size_t)i * IN + f]     * W[(f) * OUT + o];
        a1 += x[(size_t)i * IN + f + 1] * W[(f + 1) * OUT + o];
        a2 += x[(size_t)i * IN + f + 2] * W[(f + 2) * OUT + o];
        a3 += x[(size_t)i * IN + f + 3] * W[(f + 3) * OUT + o];
    }
#pragma unroll
    for (int f = IN & ~3; f < IN; ++f) a0 += x[(size_t)i * IN + f] * W[f * OUT + o];
    y[t] = (a0 + a1) + (a2 + a3);
}

// ---------------------------------------------------------------- scores
template<int H, int C>
__global__ void scores_kernel(const float* __restrict__ xw, const float* __restrict__ att,
                              float* __restrict__ sd, float* __restrict__ ss, int total) {
    int t = blockIdx.x * blockDim.x + threadIdx.x;
    if (t >= total * H) return;
    int h = t % H;
    int i = t / H;
    float d = 0.f, s = 0.f;
#pragma unroll
    for (int c = 0; c < C; ++c) {
        float v = xw[(size_t)i * H * C + h * C + c];
        d += v * att[h * 2 * C + c];
        s += v * att[h * 2 * C + C + c];
    }
    sd[t] = d;
    ss[t] = s;
}

// ---------------------------------------------------------------- gat gather (online softmax)
template<int H, int C>
__global__ void gat_kernel(const float* __restrict__ xw, const float* __restrict__ sd,
                           const float* __restrict__ ss, const int* __restrict__ idx,
                           const float* __restrict__ bias, float slope,
                           float* __restrict__ out, int total) {
    int t = blockIdx.x * blockDim.x + threadIdx.x;
    if (t >= total * H * C) return;
    int c = t % C;
    int h = (t / C) % H;
    int i = t / (H * C);
    const int* ip = idx + (size_t)i * KTOT;
    float sdi = sd[(size_t)i * H + h];
    float m = -1e30f, l = 0.f, acc = 0.f;
    for (int k = 0; k < KTOT; ++k) {
        int j = ip[k];
        float e = sdi + ss[(size_t)j * H + h];
        e = (e >= 0.f) ? e : slope * e;
        float mn = fmaxf(m, e);
        float sc = __expf(m - mn);
        float w  = __expf(e - mn);
        l   = l * sc + w;
        acc = acc * sc + w * xw[(size_t)j * H * C + h * C + c];
        m = mn;
    }
    float r = acc / l;
    if (bias) r += bias[h * C + c];
    out[t] = r;
}

// ---------------------------------------------------------------- prelu
__global__ void prelu_kernel(float* __restrict__ h, const float* __restrict__ p, int n) {
    int i = blockIdx.x * blockDim.x + threadIdx.x;
    if (i >= n) return;
    float v = h[i];
    h[i] = (v >= 0.f) ? v : p[0] * v;
}

// ---------------------------------------------------------------- bn stats (one block per channel)
__global__ void bn_stats_kernel(const float* __restrict__ h, float* __restrict__ stats,
                                int rows, int C) {
    int c = blockIdx.x;
    float s = 0.f, s2 = 0.f;
    for (int r = threadIdx.x; r < rows; r += blockDim.x) {
        float v = h[(size_t)r * C + c];
        s  += v;
        s2 += v * v;
    }
#pragma unroll
    for (int off = 32; off > 0; off >>= 1) {
        s  += __shfl_down(s, off);
        s2 += __shfl_down(s2, off);
    }
    __shared__ float red[2][4];
    int wave = threadIdx.x >> 6;
    int lane = threadIdx.x & 63;
    if (lane == 0) { red[0][wave] = s; red[1][wave] = s2; }
    __syncthreads();
    if (threadIdx.x == 0) {
        float S = 0.f, S2 = 0.f;
        int nw = blockDim.x >> 6;
        for (int w = 0; w < nw; ++w) { S += red[0][w]; S2 += red[1][w]; }
        float mean = S / rows;
        float var  = S2 / rows - mean * mean;
        stats[c * 2]     = mean;
        stats[c * 2 + 1] = rsqrtf(var + BN_EPS);
    }
}

// ---------------------------------------------------------------- bn apply
__global__ void bn_apply_kernel(float* __restrict__ h, const float* __restrict__ stats,
                                const float* __restrict__ g, const float* __restrict__ be,
                                int total, int C) {
    int t = blockIdx.x * blockDim.x + threadIdx.x;
    if (t >= total * C) return;
    int c = t % C;
    h[t] = (h[t] - stats[c * 2]) * stats[c * 2 + 1] * g[c] + be[c];
}

// ---------------------------------------------------------------- final
__global__ void final_kernel(const float* __restrict__ g3, const float* __restrict__ b3,
                             const float* __restrict__ Wc, const float* __restrict__ bc,
                             float* __restrict__ out, int total) {
    int t = blockIdx.x * blockDim.x + threadIdx.x;
    if (t >= total * 16) return;
    int o = t & 15;
    int i = t >> 4;
    float acc = bc[o];
#pragma unroll
    for (int c = 0; c < 6; ++c) {
        float hm = 0.f;
#pragma unroll
        for (int h = 0; h < 8; ++h) hm += g3[(size_t)i * 48 + h * 6 + c];
        hm = hm * 0.125f + b3[c];
        acc += hm * Wc[c * 16 + o];
    }
    out[t] = acc;
}

static inline int cdiv(int a, int b) { return (a + b - 1) / b; }

extern "C" void kernel_launch(void* const* d_in, const int* in_sizes, int n_in,
                              void* d_out, int out_size, void* d_ws, size_t ws_size,
                              hipStream_t stream) {
    const float* x    = (const float*)d_in[0];
    const float* W1   = (const float*)d_in[2];
    const float* att1 = (const float*)d_in[3];
    const float* b1   = (const float*)d_in[4];
    const float* p1   = (const float*)d_in[5];
    const float* g1   = (const float*)d_in[6];
    const float* be1  = (const float*)d_in[7];
    const float* W2   = (const float*)d_in[8];
    const float* att2 = (const float*)d_in[9];
    const float* b2   = (const float*)d_in[10];
    const float* p2   = (const float*)d_in[11];
    const float* g2   = (const float*)d_in[12];
    const float* be2  = (const float*)d_in[13];
    const float* W3   = (const float*)d_in[14];
    const float* att3 = (const float*)d_in[15];
    const float* b3   = (const float*)d_in[16];
    const float* Wc   = (const float*)d_in[17];
    const float* bc   = (const float*)d_in[18];

    const int B = 8, N = 2048, T = B * N;
    (void)n_in; (void)in_sizes; (void)out_size;

    // ---- workspace layout: persistent buffers first, then a shared region
    // that holds D (during KNN) and later xw (they are never live together).
    float* ws    = (float*)d_ws;
    float* bufA  = ws;                            // T*64
    float* bufB  = bufA + (size_t)T * 64;         // T*128
    float* bufC  = bufB + (size_t)T * 128;        // T*48
    float* sd    = bufC + (size_t)T * 48;         // T*8
    float* ss    = sd   + (size_t)T * 8;          // T*8
    float* sq    = ss   + (size_t)T * 8;          // T
    float* stats = sq   + T;                      // 256
    int*   idx   = (int*)(stats + 256);           // T*33
    float* Dxw   = (float*)(idx + (size_t)T * KTOT); // max(T*128, PB*N*N)
    float* xw    = Dxw;

    size_t fixed_words = (size_t)(Dxw - ws);
    size_t avail_words = (ws_size / 4 > fixed_words) ? (ws_size / 4 - fixed_words) : 0;
    int PB = (int)(avail_words / ((size_t)N * N));
    if (PB < 1) PB = 1;
    if (PB > B) PB = B;

    const int BS = 256;

    // ================= Layer 1 (F=3 -> H=4,C=16 -> 64) =================
    sqnorm_kernel<3><<<cdiv(T, BS), BS, 0, stream>>>(x, sq, T);
    for (int b0 = 0; b0 < B; b0 += PB) {
        int pb = (b0 + PB <= B) ? PB : (B - b0);
        dist_kernel<3><<<dim3(N / 64, N / 64, pb), 256, 0, stream>>>(
            x + (size_t)b0 * N * 3, sq + (size_t)b0 * N, Dxw, N);
        knn_select_kernel<<<pb * N, 256, 0, stream>>>(Dxw, idx, b0, N);
    }
    linear_kernel<3, 64><<<cdiv(T * 64, BS), BS, 0, stream>>>(x, W1, xw, T);
    scores_kernel<4, 16><<<cdiv(T * 4, BS), BS, 0, stream>>>(xw, att1, sd, ss, T);
    gat_kernel<4, 16><<<cdiv(T * 64, BS), BS, 0, stream>>>(xw, sd, ss, idx, b1, 0.2f, bufA, T);
    prelu_kernel<<<cdiv(T * 64, BS), BS, 0, stream>>>(bufA, p1, T * 64);
    bn_stats_kernel<<<64, 256, 0, stream>>>(bufA, stats, T, 64);
    bn_apply_kernel<<<cdiv(T * 64, BS), BS, 0, stream>>>(bufA, stats, g1, be1, T, 64);

    // ================= Layer 2 (F=64 -> H=2,C=64 -> 128) =================
    sqnorm_kernel<64><<<cdiv(T, BS), BS, 0, stream>>>(bufA, sq, T);
    for (int b0 = 0; b0 < B; b0 += PB) {
        int pb = (b0 + PB <= B) ? PB : (B - b0);
        dist_kernel<64><<<dim3(N / 64, N / 64, pb), 256, 0, stream>>>(
            bufA + (size_t)b0 * N * 64, sq + (size_t)b0 * N, Dxw, N);
        knn_select_kernel<<<pb * N, 256, 0, stream>>>(Dxw, idx, b0, N);
    }
    linear_kernel<64, 128><<<cdiv(T * 128, BS), BS, 0, stream>>>(bufA, W2, xw, T);
    scores_kernel<2, 64><<<cdiv(T * 2, BS), BS, 0, stream>>>(xw, att2, sd, ss, T);
    gat_kernel<2, 64><<<cdiv(T * 128, BS), BS, 0, stream>>>(xw, sd, ss, idx, b2, 0.2f, bufB, T);
    prelu_kernel<<<cdiv(T * 128, BS), BS, 0, stream>>>(bufB, p2, T * 128);
    bn_stats_kernel<<<128, 256, 0, stream>>>(bufB, stats, T, 128);
    bn_apply_kernel<<<cdiv(T * 128, BS), BS, 0, stream>>>(bufB, stats, g2, be2, T, 128);

    // ================= Layer 3 (F=128 -> H=8,C=6 -> mean -> 6) =================
    sqnorm_kernel<128><<<cdiv(T, BS), BS, 0, stream>>>(bufB, sq, T);
    for (int b0 = 0; b0 < B; b0 += PB) {
        int pb = (b0 + PB <= B) ? PB : (B - b0);
        dist_kernel<128><<<dim3(N / 64, N / 64, pb), 256, 0, stream>>>(
            bufB + (size_t)b0 * N * 128, sq + (size_t)b0 * N, Dxw, N);
        knn_select_kernel<<<pb * N, 256, 0, stream>>>(Dxw, idx, b0, N);
    }
    linear_kernel<128, 48><<<cdiv(T * 48, BS), BS, 0, stream>>>(bufB, W3, xw, T);
    scores_kernel<8, 6><<<cdiv(T * 8, BS), BS, 0, stream>>>(xw, att3, sd, ss, T);
    gat_kernel<8, 6><<<cdiv(T * 48, BS), BS, 0, stream>>>(xw, sd, ss, idx, nullptr, 0.5f, bufC, T);

    // ================= Final =================
    final_kernel<<<cdiv(T * 16, BS), BS, 0, stream>>>(bufC, b3, Wc, bc, (float*)d_out, T);
}

// Round 3
// 823.572 us; speedup vs baseline: 7.2243x; 1.2482x over previous
//
#include <hip/hip_runtime.h>
#include <hip/hip_bf16.h>

#define K_NN 32
#define KTOT 33
#define BN_EPS 1e-5f

typedef unsigned int uint32;
typedef unsigned long long ulong64;

__device__ __forceinline__ uint32 key_of(float f) {
    uint32 u = __float_as_uint(f);
    return u ^ ((u & 0x80000000u) ? 0xFFFFFFFFu : 0x80000000u);
}

// ---------------------------------------------------------------- sq norms
template<int F>
__global__ void sqnorm_kernel(const float* __restrict__ x, float* __restrict__ sq, int total) {
    int i = blockIdx.x * blockDim.x + threadIdx.x;
    if (i >= total) return;
    float s = 0.f;
#pragma unroll
    for (int f = 0; f < F; ++f) { float v = x[(size_t)i * F + f]; s += v * v; }
    sq[i] = s;
}

// ---------------------------------------------------------------- distance matrix
// grid = (N/64, N/64, PB), block = 256. Thread computes a 4x4 patch of D.
template<int F>
__global__ __launch_bounds__(256) void dist_kernel(
        const float* __restrict__ X, const float* __restrict__ sq,
        float* __restrict__ D, int N) {
    constexpr int KF = (F < 32) ? F : 32;
    __shared__ float As[KF][68];
    __shared__ float Bs[KF][68];
    int bz = blockIdx.z;
    const float* Xb  = X  + (size_t)bz * N * F;
    const float* sqb = sq + (size_t)bz * N;
    float* Db = D + (size_t)bz * N * N;
    int r0 = blockIdx.y * 64, c0 = blockIdx.x * 64;
    int tid = threadIdx.x;
    int tx = tid & 15, ty = tid >> 4;
    float acc[4][4] = {};
    for (int f0 = 0; f0 < F; f0 += KF) {
        __syncthreads();
        for (int e = tid; e < 64 * KF; e += 256) {
            int r = e / KF, k = e - r * KF;
            As[k][r] = Xb[(size_t)(r0 + r) * F + f0 + k];
            Bs[k][r] = Xb[(size_t)(c0 + r) * F + f0 + k];
        }
        __syncthreads();
#pragma unroll
        for (int k = 0; k < KF; ++k) {
            float a0 = As[k][ty * 4], a1 = As[k][ty * 4 + 1],
                  a2 = As[k][ty * 4 + 2], a3 = As[k][ty * 4 + 3];
            float b0 = Bs[k][tx * 4], b1 = Bs[k][tx * 4 + 1],
                  b2 = Bs[k][tx * 4 + 2], b3 = Bs[k][tx * 4 + 3];
            acc[0][0] += a0 * b0; acc[0][1] += a0 * b1; acc[0][2] += a0 * b2; acc[0][3] += a0 * b3;
            acc[1][0] += a1 * b0; acc[1][1] += a1 * b1; acc[1][2] += a1 * b2; acc[1][3] += a1 * b3;
            acc[2][0] += a2 * b0; acc[2][1] += a2 * b1; acc[2][2] += a2 * b2; acc[2][3] += a2 * b3;
            acc[3][0] += a3 * b0; acc[3][1] += a3 * b1; acc[3][2] += a3 * b2; acc[3][3] += a3 * b3;
        }
    }
    float sr[4], sc[4];
#pragma unroll
    for (int i = 0; i < 4; ++i) { sr[i] = sqb[r0 + ty * 4 + i]; sc[i] = sqb[c0 + tx * 4 + i]; }
#pragma unroll
    for (int i = 0; i < 4; ++i) {
        int gr = r0 + ty * 4 + i;
#pragma unroll
        for (int j = 0; j < 4; ++j) {
            int gc = c0 + tx * 4 + j;
            float d = sr[i] + sc[j] - 2.f * acc[i][j];
            if (gr == gc) d = 1e30f;
            Db[(size_t)gr * N + gc] = d;
        }
    }
}

// ---------------------------------------------------------------- wave-synchronous radix top-32
// One 64-lane wave per row, 4 rows per 256-thread block. Zero __syncthreads:
// per-wave LDS key buffer + per-wave histogram; wave scan via shfl; ballot
// collection with lane-uniform running offsets. Tie-break = smallest index.
template<int N>
__global__ __launch_bounds__(256) void knn_select_kernel(
        const float* __restrict__ D, int* __restrict__ idx_out, int b0) {
    __shared__ uint32 keys[4][N];
    __shared__ int    hist[4][256];
    int wv = threadIdx.x >> 6;
    int ln = threadIdx.x & 63;
    int row = blockIdx.x * 4 + wv;
    int b   = b0 + row / N;
    int i   = row & (N - 1);
    const float4* drow4 = (const float4*)(D + (size_t)row * N);

    // stage keys (single global read of the row)
#pragma unroll
    for (int c = 0; c < N / 256; ++c) {
        float4 v = drow4[c * 64 + ln];
        int p = (c * 64 + ln) * 4;
        keys[wv][p]     = key_of(v.x);
        keys[wv][p + 1] = key_of(v.y);
        keys[wv][p + 2] = key_of(v.z);
        keys[wv][p + 3] = key_of(v.w);
    }

    uint32 prefix = 0;
    int need = K_NN;
#pragma unroll
    for (int shift = 24; shift >= 0; shift -= 8) {
        // clear this wave's hist
#pragma unroll
        for (int t = 0; t < 4; ++t) hist[wv][ln * 4 + t] = 0;
        uint32 himask = (uint32)(~((1ull << (shift + 8)) - 1ull));
#pragma unroll
        for (int c = 0; c < N / 64; ++c) {
            uint32 k = keys[wv][c * 64 + ln];
            if (((k ^ prefix) & himask) == 0)
                atomicAdd(&hist[wv][(k >> shift) & 255], 1);
        }
        int h0 = hist[wv][4 * ln], h1 = hist[wv][4 * ln + 1],
            h2 = hist[wv][4 * ln + 2], h3 = hist[wv][4 * ln + 3];
        int s0 = h0, s1 = s0 + h1, s2 = s1 + h2, s3 = s2 + h3;
        int run = s3;
#pragma unroll
        for (int off = 1; off < 64; off <<= 1) {
            int v = __shfl_up(run, off, 64);
            if (ln >= off) run += v;
        }
        int ex = run - s3;   // exclusive sum before this lane's 4 bins
        int fbin = -1, fex = 0;
        if      (ex      < need && ex + s0 >= need) { fbin = 4 * ln;     fex = ex; }
        else if (ex + s0 < need && ex + s1 >= need) { fbin = 4 * ln + 1; fex = ex + s0; }
        else if (ex + s1 < need && ex + s2 >= need) { fbin = 4 * ln + 2; fex = ex + s1; }
        else if (ex + s2 < need && ex + s3 >= need) { fbin = 4 * ln + 3; fex = ex + s2; }
        ulong64 bm = __ballot(fbin >= 0);
        int srcl = __ffsll(bm) - 1;
        int bin  = __shfl(fbin, srcl, 64);
        int bex  = __shfl(fex,  srcl, 64);
        prefix |= ((uint32)bin) << shift;
        need -= bex;
    }
    // prefix = key of the 32nd smallest; cl = #strictly-less, need = eq-slots
    int cl = K_NN - need;
    int gbase = b * N;
    int* op = idx_out + (size_t)(gbase + i) * KTOT;
    int offl = 0, offe = 0;
#pragma unroll
    for (int c = 0; c < N / 64; ++c) {
        uint32 k = keys[wv][c * 64 + ln];
        bool less = (k < prefix);
        bool eq   = (k == prefix);
        ulong64 bl = __ballot(less);
        ulong64 be = __ballot(eq);
        ulong64 lom = (1ull << ln) - 1ull;
        int j = c * 64 + ln;
        if (less) op[offl + __popcll(bl & lom)] = gbase + j;
        if (eq) {
            int slot = cl + offe + __popcll(be & lom);
            if (slot < K_NN) op[slot] = gbase + j;
        }
        offl += __popcll(bl);
        offe += __popcll(be);
    }
    if (ln == 0) op[K_NN] = gbase + i;
}

// ---------------------------------------------------------------- linear
template<int IN, int OUT>
__global__ void linear_kernel(const float* __restrict__ x, const float* __restrict__ W,
                              float* __restrict__ y, int total) {
    int t = blockIdx.x * blockDim.x + threadIdx.x;
    if (t >= total * OUT) return;
    int o = t % OUT;
    int i = t / OUT;
    float a0 = 0.f, a1 = 0.f, a2 = 0.f, a3 = 0.f;
#pragma unroll
    for (int f = 0; f + 3 < IN; f += 4) {
        a0 += x[(size_t)i * IN + f]     * W[(f) * OUT + o];
        a1 += x[(size_t)i * IN + f + 1] * W[(f + 1) * OUT + o];
        a2 += x[(size_t)i * IN + f + 2] * W[(f + 2) * OUT + o];
        a3 += x[(size_t)i * IN + f + 3] * W[(f + 3) * OUT + o];
    }
#pragma unroll
    for (int f = IN & ~3; f < IN; ++f) a0 += x[(size_t)i * IN + f] * W[f * OUT + o];
    y[t] = (a0 + a1) + (a2 + a3);
}

// ---------------------------------------------------------------- scores
template<int H, int C>
__global__ void scores_kernel(const float* __restrict__ xw, const float* __restrict__ att,
                              float* __restrict__ sd, float* __restrict__ ss, int total) {
    int t = blockIdx.x * blockDim.x + threadIdx.x;
    if (t >= total * H) return;
    int h = t % H;
    int i = t / H;
    float d = 0.f, s = 0.f;
#pragma unroll
    for (int c = 0; c < C; ++c) {
        float v = xw[(size_t)i * H * C + h * C + c];
        d += v * att[h * 2 * C + c];
        s += v * att[h * 2 * C + C + c];
    }
    sd[t] = d;
    ss[t] = s;
}

// ---------------------------------------------------------------- gat gather (online softmax)
template<int H, int C>
__global__ void gat_kernel(const float* __restrict__ xw, const float* __restrict__ sd,
                           const float* __restrict__ ss, const int* __restrict__ idx,
                           const float* __restrict__ bias, float slope,
                           float* __restrict__ out, int total) {
    int t = blockIdx.x * blockDim.x + threadIdx.x;
    if (t >= total * H * C) return;
    int c = t % C;
    int h = (t / C) % H;
    int i = t / (H * C);
    const int* ip = idx + (size_t)i * KTOT;
    float sdi = sd[(size_t)i * H + h];
    float m = -1e30f, l = 0.f, acc = 0.f;
    for (int k = 0; k < KTOT; ++k) {
        int j = ip[k];
        float e = sdi + ss[(size_t)j * H + h];
        e = (e >= 0.f) ? e : slope * e;
        float mn = fmaxf(m, e);
        float sc = __expf(m - mn);
        float w  = __expf(e - mn);
        l   = l * sc + w;
        acc = acc * sc + w * xw[(size_t)j * H * C + h * C + c];
        m = mn;
    }
    float r = acc / l;
    if (bias) r += bias[h * C + c];
    out[t] = r;
}

// ---------------------------------------------------------------- prelu
__global__ void prelu_kernel(float* __restrict__ h, const float* __restrict__ p, int n) {
    int i = blockIdx.x * blockDim.x + threadIdx.x;
    if (i >= n) return;
    float v = h[i];
    h[i] = (v >= 0.f) ? v : p[0] * v;
}

// ---------------------------------------------------------------- bn stats (one block per channel)
__global__ void bn_stats_kernel(const float* __restrict__ h, float* __restrict__ stats,
                                int rows, int C) {
    int c = blockIdx.x;
    float s = 0.f, s2 = 0.f;
    for (int r = threadIdx.x; r < rows; r += blockDim.x) {
        float v = h[(size_t)r * C + c];
        s  += v;
        s2 += v * v;
    }
#pragma unroll
    for (int off = 32; off > 0; off >>= 1) {
        s  += __shfl_down(s, off);
        s2 += __shfl_down(s2, off);
    }
    __shared__ float red[2][4];
    int wave = threadIdx.x >> 6;
    int lane = threadIdx.x & 63;
    if (lane == 0) { red[0][wave] = s; red[1][wave] = s2; }
    __syncthreads();
    if (threadIdx.x == 0) {
        float S = 0.f, S2 = 0.f;
        int nw = blockDim.x >> 6;
        for (int w = 0; w < nw; ++w) { S += red[0][w]; S2 += red[1][w]; }
        float mean = S / rows;
        float var  = S2 / rows - mean * mean;
        stats[c * 2]     = mean;
        stats[c * 2 + 1] = rsqrtf(var + BN_EPS);
    }
}

// ---------------------------------------------------------------- bn apply
__global__ void bn_apply_kernel(float* __restrict__ h, const float* __restrict__ stats,
                                const float* __restrict__ g, const float* __restrict__ be,
                                int total, int C) {
    int t = blockIdx.x * blockDim.x + threadIdx.x;
    if (t >= total * C) return;
    int c = t % C;
    h[t] = (h[t] - stats[c * 2]) * stats[c * 2 + 1] * g[c] + be[c];
}

// ---------------------------------------------------------------- final
__global__ void final_kernel(const float* __restrict__ g3, const float* __restrict__ b3,
                             const float* __restrict__ Wc, const float* __restrict__ bc,
                             float* __restrict__ out, int total) {
    int t = blockIdx.x * blockDim.x + threadIdx.x;
    if (t >= total * 16) return;
    int o = t & 15;
    int i = t >> 4;
    float acc = bc[o];
#pragma unroll
    for (int c = 0; c < 6; ++c) {
        float hm = 0.f;
#pragma unroll
        for (int h = 0; h < 8; ++h) hm += g3[(size_t)i * 48 + h * 6 + c];
        hm = hm * 0.125f + b3[c];
        acc += hm * Wc[c * 16 + o];
    }
    out[t] = acc;
}

static inline int cdiv(int a, int b) { return (a + b - 1) / b; }

extern "C" void kernel_launch(void* const* d_in, const int* in_sizes, int n_in,
                              void* d_out, int out_size, void* d_ws, size_t ws_size,
                              hipStream_t stream) {
    const float* x    = (const float*)d_in[0];
    const float* W1   = (const float*)d_in[2];
    const float* att1 = (const float*)d_in[3];
    const float* b1   = (const float*)d_in[4];
    const float* p1   = (const float*)d_in[5];
    const float* g1   = (const float*)d_in[6];
    const float* be1  = (const float*)d_in[7];
    const float* W2   = (const float*)d_in[8];
    const float* att2 = (const float*)d_in[9];
    const float* b2   = (const float*)d_in[10];
    const float* p2   = (const float*)d_in[11];
    const float* g2   = (const float*)d_in[12];
    const float* be2  = (const float*)d_in[13];
    const float* W3   = (const float*)d_in[14];
    const float* att3 = (const float*)d_in[15];
    const float* b3   = (const float*)d_in[16];
    const float* Wc   = (const float*)d_in[17];
    const float* bc   = (const float*)d_in[18];

    const int B = 8, N = 2048, T = B * N;
    (void)n_in; (void)in_sizes; (void)out_size;

    // ---- workspace layout: persistent buffers first, then a shared region
    // that holds D (during KNN) and later xw (they are never live together).
    float* ws    = (float*)d_ws;
    float* bufA  = ws;                            // T*64
    float* bufB  = bufA + (size_t)T * 64;         // T*128
    float* bufC  = bufB + (size_t)T * 128;        // T*48
    float* sd    = bufC + (size_t)T * 48;         // T*8
    float* ss    = sd   + (size_t)T * 8;          // T*8
    float* sq    = ss   + (size_t)T * 8;          // T
    float* stats = sq   + T;                      // 256
    int*   idx   = (int*)(stats + 256);           // T*33
    float* Dxw   = (float*)(idx + (size_t)T * KTOT); // max(T*128, PB*N*N)
    float* xw    = Dxw;

    size_t fixed_words = (size_t)(Dxw - ws);
    size_t avail_words = (ws_size / 4 > fixed_words) ? (ws_size / 4 - fixed_words) : 0;
    int PB = (int)(avail_words / ((size_t)N * N));
    if (PB < 1) PB = 1;
    if (PB > B) PB = B;

    const int BS = 256;

    // ================= Layer 1 (F=3 -> H=4,C=16 -> 64) =================
    sqnorm_kernel<3><<<cdiv(T, BS), BS, 0, stream>>>(x, sq, T);
    for (int b0 = 0; b0 < B; b0 += PB) {
        int pb = (b0 + PB <= B) ? PB : (B - b0);
        dist_kernel<3><<<dim3(N / 64, N / 64, pb), 256, 0, stream>>>(
            x + (size_t)b0 * N * 3, sq + (size_t)b0 * N, Dxw, N);
        knn_select_kernel<2048><<<pb * N / 4, 256, 0, stream>>>(Dxw, idx, b0);
    }
    linear_kernel<3, 64><<<cdiv(T * 64, BS), BS, 0, stream>>>(x, W1, xw, T);
    scores_kernel<4, 16><<<cdiv(T * 4, BS), BS, 0, stream>>>(xw, att1, sd, ss, T);
    gat_kernel<4, 16><<<cdiv(T * 64, BS), BS, 0, stream>>>(xw, sd, ss, idx, b1, 0.2f, bufA, T);
    prelu_kernel<<<cdiv(T * 64, BS), BS, 0, stream>>>(bufA, p1, T * 64);
    bn_stats_kernel<<<64, 256, 0, stream>>>(bufA, stats, T, 64);
    bn_apply_kernel<<<cdiv(T * 64, BS), BS, 0, stream>>>(bufA, stats, g1, be1, T, 64);

    // ================= Layer 2 (F=64 -> H=2,C=64 -> 128) =================
    sqnorm_kernel<64><<<cdiv(T, BS), BS, 0, stream>>>(bufA, sq, T);
    for (int b0 = 0; b0 < B; b0 += PB) {
        int pb = (b0 + PB <= B) ? PB : (B - b0);
        dist_kernel<64><<<dim3(N / 64, N / 64, pb), 256, 0, stream>>>(
            bufA + (size_t)b0 * N * 64, sq + (size_t)b0 * N, Dxw, N);
        knn_select_kernel<2048><<<pb * N / 4, 256, 0, stream>>>(Dxw, idx, b0);
    }
    linear_kernel<64, 128><<<cdiv(T * 128, BS), BS, 0, stream>>>(bufA, W2, xw, T);
    scores_kernel<2, 64><<<cdiv(T * 2, BS), BS, 0, stream>>>(xw, att2, sd, ss, T);
    gat_kernel<2, 64><<<cdiv(T * 128, BS), BS, 0, stream>>>(xw, sd, ss, idx, b2, 0.2f, bufB, T);
    prelu_kernel<<<cdiv(T * 128, BS), BS, 0, stream>>>(bufB, p2, T * 128);
    bn_stats_kernel<<<128, 256, 0, stream>>>(bufB, stats, T, 128);
    bn_apply_kernel<<<cdiv(T * 128, BS), BS, 0, stream>>>(bufB, stats, g2, be2, T, 128);

    // ================= Layer 3 (F=128 -> H=8,C=6 -> mean -> 6) =================
    sqnorm_kernel<128><<<cdiv(T, BS), BS, 0, stream>>>(bufB, sq, T);
    for (int b0 = 0; b0 < B; b0 += PB) {
        int pb = (b0 + PB <= B) ? PB : (B - b0);
        dist_kernel<128><<<dim3(N / 64, N / 64, pb), 256, 0, stream>>>(
            bufB + (size_t)b0 * N * 128, sq + (size_t)b0 * N, Dxw, N);
        knn_select_kernel<2048><<<pb * N / 4, 256, 0, stream>>>(Dxw, idx, b0);
    }
    linear_kernel<128, 48><<<cdiv(T * 48, BS), BS, 0, stream>>>(bufB, W3, xw, T);
    scores_kernel<8, 6><<<cdiv(T * 8, BS), BS, 0, stream>>>(xw, att3, sd, ss, T);
    gat_kernel<8, 6><<<cdiv(T * 48, BS), BS, 0, stream>>>(xw, sd, ss, idx, nullptr, 0.5f, bufC, T);

    // ================= Final =================
    final_kernel<<<cdiv(T * 16, BS), BS, 0, stream>>>(bufC, b3, Wc, bc, (float*)d_out, T);
}